// Round 6
// baseline (621.574 us; speedup 1.0000x reference)
//
#include <hip/hip_runtime.h>
#include <cstdint>
#include <cstddef>

#define ALPHA 0.2f
// N=8192, Fin=512, Fout=256 hard-coded per problem instance.

typedef __attribute__((ext_vector_type(8)))  short short8;   // 8 bf16 (4 VGPRs)
typedef __attribute__((ext_vector_type(16))) float f32x16;   // 32x32 MFMA acc

static __device__ __forceinline__ unsigned short f2bf(float x) {
  union { float f; unsigned u; } c; c.f = x;
  unsigned u = c.u;
  unsigned r = (u + 0x7FFFu + ((u >> 16) & 1u)) >> 16;  // RNE
  return (unsigned short)r;
}

// ---------------- Kernel A: Wh = h @ W  (fp32, 8192x512 * 512x256) ----------
// Round-0 tile: BM=128, BN=64, BK=32, 256 threads, 8x4/thread, 2 blocks/CU.
__global__ __launch_bounds__(256, 2) void gemm1(const float* __restrict__ h,
                                                const float* __restrict__ W,
                                                float* __restrict__ Wh) {
  __shared__ float As[32][132];  // [k][m], padded
  __shared__ float Bs[32][64];   // [k][n]
  const int t = threadIdx.x;
  const int bid = blockIdx.x;
  const int nb = bid & 3, mb = bid >> 2;
  const int m0 = mb * 128, n0 = nb * 64;
  const int ty = t >> 4, tx = t & 15;   // rows ty*8.., cols tx*4..
  float acc[8][4];
#pragma unroll
  for (int i = 0; i < 8; i++)
#pragma unroll
    for (int j = 0; j < 4; j++) acc[i][j] = 0.f;

  for (int k0 = 0; k0 < 512; k0 += 32) {
#pragma unroll
    for (int c = 0; c < 4; c++) {                 // stage A with transpose
      int m = c * 32 + (t >> 3);
      int kq = (t & 7) * 4;
      float4 v = *(const float4*)&h[(size_t)(m0 + m) * 512 + k0 + kq];
      As[kq + 0][m] = v.x; As[kq + 1][m] = v.y;
      As[kq + 2][m] = v.z; As[kq + 3][m] = v.w;
    }
#pragma unroll
    for (int c = 0; c < 2; c++) {                 // stage B
      int k = c * 16 + (t >> 4);
      int n = (t & 15) * 4;
      *(float4*)&Bs[k][n] = *(const float4*)&W[(size_t)(k0 + k) * 256 + n0 + n];
    }
    __syncthreads();
#pragma unroll
    for (int k = 0; k < 32; k++) {
      float4 a0 = *(float4*)&As[k][ty * 8];
      float4 a1 = *(float4*)&As[k][ty * 8 + 4];
      float4 b  = *(float4*)&Bs[k][tx * 4];
      float av[8] = {a0.x, a0.y, a0.z, a0.w, a1.x, a1.y, a1.z, a1.w};
      float bv[4] = {b.x, b.y, b.z, b.w};
#pragma unroll
      for (int i = 0; i < 8; i++)
#pragma unroll
        for (int j = 0; j < 4; j++) acc[i][j] = fmaf(av[i], bv[j], acc[i][j]);
    }
    __syncthreads();
  }
#pragma unroll
  for (int i = 0; i < 8; i++) {
    float4 v = {acc[i][0], acc[i][1], acc[i][2], acc[i][3]};
    *(float4*)&Wh[(size_t)(m0 + ty * 8 + i) * 256 + n0 + tx * 4] = v;
  }
}

// ------------- Kernel B: per-row f1,f2 and u/v pack (verbatim) --------------
__global__ __launch_bounds__(256) void rowstats(const float* __restrict__ Wh,
                                                const float* __restrict__ a,
                                                float* __restrict__ f1,
                                                float* __restrict__ f2,
                                                unsigned* __restrict__ uvpack) {
  const int t = threadIdx.x;
  const int w = t >> 6, lane = t & 63;
  const int i = blockIdx.x * 4 + w;
  float4 wv = *(const float4*)&Wh[(size_t)i * 256 + lane * 4];
  float4 a1 = *(const float4*)&a[lane * 4];
  float4 a2 = *(const float4*)&a[256 + lane * 4];
  float s1 = wv.x * a1.x + wv.y * a1.y + wv.z * a1.z + wv.w * a1.w;
  float s2 = wv.x * a2.x + wv.y * a2.y + wv.z * a2.z + wv.w * a2.w;
#pragma unroll
  for (int off = 32; off; off >>= 1) { s1 += __shfl_xor(s1, off); s2 += __shfl_xor(s2, off); }
  if (lane == 0) {
    f1[i] = s1; f2[i] = s2;
    float u = __expf(s2), v = __expf(ALPHA * s2);
    uvpack[i] = (unsigned)f2bf(u) | ((unsigned)f2bf(v) << 16);
  }
}

// ------------- Kernel B2: LDS-tiled transpose (verbatim) --------------------
__global__ __launch_bounds__(256) void wtrans(const float* __restrict__ Wh,
                                              unsigned short* __restrict__ WhT) {
  __shared__ unsigned short T[64][80];   // 80-short stride
  const int t = threadIdx.x;
  const int bi = blockIdx.x & 127;
  const int bc = blockIdx.x >> 7;
  const int i0 = bi * 64, c0 = bc * 64;
  {
    const int il = t >> 2, cq = (t & 3) * 16;
#pragma unroll
    for (int k = 0; k < 4; ++k) {
      float4 v = *(const float4*)&Wh[(size_t)(i0 + il) * 256 + c0 + cq + k * 4];
      T[cq + k * 4 + 0][il] = f2bf(v.x);
      T[cq + k * 4 + 1][il] = f2bf(v.y);
      T[cq + k * 4 + 2][il] = f2bf(v.z);
      T[cq + k * 4 + 3][il] = f2bf(v.w);
    }
  }
  __syncthreads();
  {
    const int cl = t >> 2, iq = (t & 3) * 16;
    *(uint4*)&WhT[(size_t)(c0 + cl) * 8192 + i0 + iq]     = *(const uint4*)&T[cl][iq];
    *(uint4*)&WhT[(size_t)(c0 + cl) * 8192 + i0 + iq + 8] = *(const uint4*)&T[cl][iq + 8];
  }
}

// ---------------- Kernel Bmax: F2max = max_j f2[j] --------------------------
__global__ __launch_bounds__(256) void f2max_k(const float* __restrict__ f2,
                                               float* __restrict__ f2maxp) {
  __shared__ float red[256];
  const int t = threadIdx.x;
  float m = -1e30f;
  for (int c = 0; c < 32; c++) m = fmaxf(m, f2[c * 256 + t]);
  red[t] = m;
  __syncthreads();
  for (int s = 128; s; s >>= 1) {
    if (t < s) red[t] = fmaxf(red[t], red[t + s]);
    __syncthreads();
  }
  if (t == 0) f2maxp[0] = red[0];
}

// ---------------- Kernel M: pack adj>0 into a bitmask (8 MB) ----------------
__global__ __launch_bounds__(256) void maskpack(const int* __restrict__ adj,
                                                unsigned long long* __restrict__ mask) {
  __shared__ unsigned long long mbuf[4][128];
  const int t = threadIdx.x, wave = t >> 6, lane = t & 63;
  const int row = blockIdx.x * 4 + wave;
  const int* ap = adj + (size_t)row * 8192 + lane;
#pragma unroll 1
  for (int it0 = 0; it0 < 128; it0 += 4) {
    int a0 = ap[(it0 + 0) * 64];
    int a1 = ap[(it0 + 1) * 64];
    int a2 = ap[(it0 + 2) * 64];
    int a3 = ap[(it0 + 3) * 64];
    unsigned long long b0 = __ballot(a0 > 0);
    unsigned long long b1 = __ballot(a1 > 0);
    unsigned long long b2 = __ballot(a2 > 0);
    unsigned long long b3 = __ballot(a3 > 0);
    if (lane == 0) {
      mbuf[wave][it0 + 0] = b0; mbuf[wave][it0 + 1] = b1;
      mbuf[wave][it0 + 2] = b2; mbuf[wave][it0 + 3] = b3;
    }
  }
  __syncthreads();
  uint4* dst = (uint4*)(mask + (size_t)blockIdx.x * 4 * 128);
  dst[t] = ((const uint4*)mbuf)[t];
}

// ---------------- Kernel C: fused masked-softmax @ Wh -----------------------
// COLUMN-SPLIT restructure: all 4 waves walk the SAME full j-range (512
// steps of 16 j); wave w owns output col-tiles 2w,2w+1 (cols 64w..64w+63).
// Per step each wave loads only 2 B-fragments -> per-CU line footprint
// 4KB/step, so the 64B lines shared by steps 2k/2k+1 stay L1-resident:
// L2 traffic = exactly one full WhT read per block, fully line-utilized
// (4x less than the j-split version). uv/mask loads are identical across
// waves -> L1 broadcast. P-compute duplicated per wave (VALU is cheap).
// Each wave's acc is FINAL for its cols; l_i comes from the wave's own
// full-j lpriv. Zero LDS, zero barriers, no combine.
#define ATTN_SUB(KSUB, MWORD, UCA, UCB, BFC, BFN, SCUR)                          \
  {                                                                              \
    const unsigned mbyte_ = ((MWORD) >> (((KSUB) & 1) * 16 + aselsh)) & 0xFFu;   \
    const unsigned uu_[8] = {UCA.x, UCA.y, UCA.z, UCA.w, UCB.x, UCB.y, UCB.z, UCB.w}; \
    float w_[8];                                                                 \
    _Pragma("unroll")                                                            \
    for (int jj = 0; jj < 8; jj++) {                                             \
      union { unsigned u; float f; } cu_, cv_;                                   \
      cu_.u = uu_[jj] << 16;                                                     \
      cv_.u = uu_[jj] & 0xFFFF0000u;                                             \
      float wv_ = (cu_.f > Ui) ? Ai * cu_.f : Bi * cv_.f;                        \
      int ext_ = ((int)(mbyte_ << (31 - jj))) >> 31;   /* bit -> 0 / all-ones */ \
      union { float f; int i; } wu_; wu_.f = wv_; wu_.i &= ext_;                 \
      w_[jj] = wu_.f;                                                            \
    }                                                                            \
    lpriv += ((w_[0] + w_[1]) + (w_[2] + w_[3])) + ((w_[4] + w_[5]) + (w_[6] + w_[7])); \
    union { uint4 q; short8 s; } af_;                                            \
    asm("v_cvt_pk_bf16_f32 %0, %1, %2" : "=v"(af_.q.x) : "v"(w_[0]), "v"(w_[1]));\
    asm("v_cvt_pk_bf16_f32 %0, %1, %2" : "=v"(af_.q.y) : "v"(w_[2]), "v"(w_[3]));\
    asm("v_cvt_pk_bf16_f32 %0, %1, %2" : "=v"(af_.q.z) : "v"(w_[4]), "v"(w_[5]));\
    asm("v_cvt_pk_bf16_f32 %0, %1, %2" : "=v"(af_.q.w) : "v"(w_[6]), "v"(w_[7]));\
    const int sn_ = (SCUR) + 1 < 512 ? (SCUR) + 1 : 511;                         \
    BFN[0] = *(const short8*)(wtp0 + (size_t)sn_ * 16);                          \
    BFN[1] = *(const short8*)(wtp1 + (size_t)sn_ * 16);                          \
    acc0 = __builtin_amdgcn_mfma_f32_32x32x16_bf16(af_.s, BFC[0], acc0, 0, 0, 0);\
    acc1 = __builtin_amdgcn_mfma_f32_32x32x16_bf16(af_.s, BFC[1], acc1, 0, 0, 0);\
  }

#define ATTN_GROUP(G, UC, UN, MC, MN)                                            \
  {                                                                              \
    const int gn_ = (G) < 127 ? (G) + 1 : 127;                                   \
    MN = mp[gn_];                                                                \
    UN[0] = *(const uint4*)(uvp + gn_ * 64 + 0);                                 \
    UN[1] = *(const uint4*)(uvp + gn_ * 64 + 4);                                 \
    ATTN_SUB(0, MC.x, UC[0], UC[1], bfA, bfB, 4 * (G) + 0);                      \
    UN[2] = *(const uint4*)(uvp + gn_ * 64 + 16);                                \
    UN[3] = *(const uint4*)(uvp + gn_ * 64 + 20);                                \
    ATTN_SUB(1, MC.x, UC[2], UC[3], bfB, bfA, 4 * (G) + 1);                      \
    UN[4] = *(const uint4*)(uvp + gn_ * 64 + 32);                                \
    UN[5] = *(const uint4*)(uvp + gn_ * 64 + 36);                                \
    ATTN_SUB(2, MC.y, UC[4], UC[5], bfA, bfB, 4 * (G) + 2);                      \
    UN[6] = *(const uint4*)(uvp + gn_ * 64 + 48);                                \
    UN[7] = *(const uint4*)(uvp + gn_ * 64 + 52);                                \
    ATTN_SUB(3, MC.y, UC[6], UC[7], bfB, bfA, 4 * (G) + 3);                      \
  }

__global__ __launch_bounds__(256, 1) void attn_main(const unsigned long long* __restrict__ maskw,
                                                    const float* __restrict__ f1,
                                                    const unsigned* __restrict__ uvpack,
                                                    const unsigned short* __restrict__ WhT,
                                                    const float* __restrict__ f2maxp,
                                                    float* __restrict__ out) {
  const int t = threadIdx.x;
  const int wave = t >> 6, lane = t & 63;
  const int am = lane & 31, asel = lane >> 5;
  const int aselsh = asel * 8;
  const int r0 = blockIdx.x * 32;
  const int row = r0 + am;

  const float F2max = f2maxp[0];
  const float f1v = f1[row];
  const float x = f1v + F2max;
  const float M = x > 0.f ? x : ALPHA * x;   // analytic per-row max bound
  const float Ai = __expf(f1v - M);
  const float Bi = __expf(ALPHA * f1v - M);
  const float Ui = __expf(-f1v);             // u_j > Ui  <=>  f1_i + f2_j > 0

  f32x16 acc0 = {}, acc1 = {};
  // full-row streams (jq = 0): mask 128 uint2/row; uv words; B rows for this
  // wave's two col-tiles: rows wave*64+am and wave*64+32+am.
  const uint2* mp = (const uint2*)maskw + (size_t)row * 128;
  const unsigned* uvp = uvpack + aselsh;
  const unsigned short* wtp0 = WhT + (size_t)(wave * 64 + am) * 8192 + aselsh;
  const unsigned short* wtp1 = wtp0 + (size_t)32 * 8192;

  // prologue: group-0 mask+uv, step-0 B-fragments
  uint2 mg = mp[0], mgN;
  uint4 ug[8], ugN[8];
#pragma unroll
  for (int k = 0; k < 4; k++) {
    ug[2 * k]     = *(const uint4*)(uvp + k * 16);
    ug[2 * k + 1] = *(const uint4*)(uvp + k * 16 + 4);
  }
  short8 bfA[2], bfB[2];
  bfA[0] = *(const short8*)(wtp0);
  bfA[1] = *(const short8*)(wtp1);
  float lpriv = 0.f;

#pragma unroll 1
  for (int gg = 0; gg < 64; ++gg) {
    ATTN_GROUP(2 * gg,     ug,  ugN, mg,  mgN);
    ATTN_GROUP(2 * gg + 1, ugN, ug,  mgN, mg);
  }

  // full row-sum: lane and lane^32 hold the two j-slot halves of row am
  lpriv += __shfl_xor(lpriv, 32);

  // normalize + ELU + store (acc is final; l[rowl] fetched via shfl)
#pragma unroll
  for (int reg = 0; reg < 16; reg++) {
    const int rowl = (reg & 3) + 8 * (reg >> 2) + 4 * asel;  // verified C/D map
    const float l = __shfl(lpriv, rowl);
    const float inv = 1.0f / fmaxf(l, 1e-30f);
    float v0 = acc0[reg] * inv;
    float v1 = acc1[reg] * inv;
    float o0 = v0 > 0.f ? v0 : __expf(v0) - 1.f;
    float o1 = v1 > 0.f ? v1 : __expf(v1) - 1.f;
    out[(size_t)(r0 + rowl) * 256 + wave * 64 + am] = o0;
    out[(size_t)(r0 + rowl) * 256 + wave * 64 + 32 + am] = o1;
  }
}

extern "C" void kernel_launch(void* const* d_in, const int* in_sizes, int n_in,
                              void* d_out, int out_size, void* d_ws, size_t ws_size,
                              hipStream_t stream) {
  const float* h  = (const float*)d_in[0];
  const int* adj  = (const int*)d_in[1];
  const float* W  = (const float*)d_in[2];
  const float* a  = (const float*)d_in[3];
  float* out = (float*)d_out;
  char* ws = (char*)d_ws;

  // ws layout:
  //  [0, 8M):    Wh fp32
  //  [8M, 16M):  mask bits (8 MB)
  //  [16M, 20M): WhT bf16 (4 MB)
  //  [20M ...):  f1 (32K), f2 (32K), uvpack (32K), f2max (128B)
  float* Wh            = (float*)ws;
  unsigned long long* mask = (unsigned long long*)(ws + (size_t)(8u << 20));
  unsigned short* WhT  = (unsigned short*)(ws + (size_t)(16u << 20));
  float* f1            = (float*)(ws + (size_t)(20u << 20));
  float* f2            = (float*)(ws + (size_t)(20u << 20) + (32u << 10));
  unsigned* uvpack     = (unsigned*)(ws + (size_t)(20u << 20) + (64u << 10));
  float* f2maxp        = (float*)(ws + (size_t)(20u << 20) + (96u << 10));

  maskpack<<<2048, 256, 0, stream>>>(adj, mask);
  gemm1<<<256, 256, 0, stream>>>(h, W, Wh);
  rowstats<<<2048, 256, 0, stream>>>(Wh, a, f1, f2, uvpack);
  wtrans<<<512, 256, 0, stream>>>(Wh, WhT);
  f2max_k<<<1, 256, 0, stream>>>(f2, f2maxp);
  attn_main<<<256, 256, 0, stream>>>(mask, f1, uvpack, WhT, f2maxp, out);
}

// Round 9
// 554.777 us; speedup vs baseline: 1.1204x; 1.1204x over previous
//
#include <hip/hip_runtime.h>
#include <cstdint>
#include <cstddef>

#define ALPHA 0.2f
// N=8192, Fin=512, Fout=256 hard-coded per problem instance.

typedef __attribute__((ext_vector_type(8)))  short short8;   // 8 bf16 (4 VGPRs)
typedef __attribute__((ext_vector_type(16))) float f32x16;   // 32x32 MFMA acc

static __device__ __forceinline__ unsigned short f2bf(float x) {
  union { float f; unsigned u; } c; c.f = x;
  unsigned u = c.u;
  unsigned r = (u + 0x7FFFu + ((u >> 16) & 1u)) >> 16;  // RNE
  return (unsigned short)r;
}

// ---------------- Kernel A: Wh = h @ W  (fp32, 8192x512 * 512x256) ----------
// Retile for occupancy: BM=64, BN=64, BK=32, 256 threads, 4x4/thread,
// grid 512 = 2 blocks/CU (vs 1 before: staging latency of one block hides
// under the other's compute). Ascending-k accumulation order preserved ->
// bit-identical Wh.
__global__ __launch_bounds__(256, 2) void gemm1(const float* __restrict__ h,
                                                const float* __restrict__ W,
                                                float* __restrict__ Wh) {
  __shared__ float As[32][68];   // [k][m], padded
  __shared__ float Bs[32][64];   // [k][n]
  const int t = threadIdx.x;
  const int bid = blockIdx.x;
  const int nb = bid & 3, mb = bid >> 2;
  const int m0 = mb * 64, n0 = nb * 64;
  const int ty = t >> 4, tx = t & 15;   // rows ty*4.., cols tx*4..
  float acc[4][4];
#pragma unroll
  for (int i = 0; i < 4; i++)
#pragma unroll
    for (int j = 0; j < 4; j++) acc[i][j] = 0.f;

  for (int k0 = 0; k0 < 512; k0 += 32) {
#pragma unroll
    for (int c = 0; c < 2; c++) {                 // stage A with transpose
      int m = c * 32 + (t >> 3);
      int kq = (t & 7) * 4;
      float4 v = *(const float4*)&h[(size_t)(m0 + m) * 512 + k0 + kq];
      As[kq + 0][m] = v.x; As[kq + 1][m] = v.y;
      As[kq + 2][m] = v.z; As[kq + 3][m] = v.w;
    }
#pragma unroll
    for (int c = 0; c < 2; c++) {                 // stage B
      int k = c * 16 + (t >> 4);
      int n = (t & 15) * 4;
      *(float4*)&Bs[k][n] = *(const float4*)&W[(size_t)(k0 + k) * 256 + n0 + n];
    }
    __syncthreads();
#pragma unroll
    for (int k = 0; k < 32; k++) {
      float4 a = *(float4*)&As[k][ty * 4];
      float4 b = *(float4*)&Bs[k][tx * 4];
      float av[4] = {a.x, a.y, a.z, a.w};
      float bv[4] = {b.x, b.y, b.z, b.w};
#pragma unroll
      for (int i = 0; i < 4; i++)
#pragma unroll
        for (int j = 0; j < 4; j++) acc[i][j] = fmaf(av[i], bv[j], acc[i][j]);
    }
    __syncthreads();
  }
#pragma unroll
  for (int i = 0; i < 4; i++) {
    float4 v = {acc[i][0], acc[i][1], acc[i][2], acc[i][3]};
    *(float4*)&Wh[(size_t)(m0 + ty * 4 + i) * 256 + n0 + tx * 4] = v;
  }
}

// ------------- Kernel B: per-row f1,f2 and u/v pack (verbatim) --------------
__global__ __launch_bounds__(256) void rowstats(const float* __restrict__ Wh,
                                                const float* __restrict__ a,
                                                float* __restrict__ f1,
                                                float* __restrict__ f2,
                                                unsigned* __restrict__ uvpack) {
  const int t = threadIdx.x;
  const int w = t >> 6, lane = t & 63;
  const int i = blockIdx.x * 4 + w;
  float4 wv = *(const float4*)&Wh[(size_t)i * 256 + lane * 4];
  float4 a1 = *(const float4*)&a[lane * 4];
  float4 a2 = *(const float4*)&a[256 + lane * 4];
  float s1 = wv.x * a1.x + wv.y * a1.y + wv.z * a1.z + wv.w * a1.w;
  float s2 = wv.x * a2.x + wv.y * a2.y + wv.z * a2.z + wv.w * a2.w;
#pragma unroll
  for (int off = 32; off; off >>= 1) { s1 += __shfl_xor(s1, off); s2 += __shfl_xor(s2, off); }
  if (lane == 0) {
    f1[i] = s1; f2[i] = s2;
    float u = __expf(s2), v = __expf(ALPHA * s2);
    uvpack[i] = (unsigned)f2bf(u) | ((unsigned)f2bf(v) << 16);
  }
}

// ------------- Kernel B2: LDS-tiled transpose (verbatim) --------------------
__global__ __launch_bounds__(256) void wtrans(const float* __restrict__ Wh,
                                              unsigned short* __restrict__ WhT) {
  __shared__ unsigned short T[64][80];   // 80-short stride
  const int t = threadIdx.x;
  const int bi = blockIdx.x & 127;
  const int bc = blockIdx.x >> 7;
  const int i0 = bi * 64, c0 = bc * 64;
  {
    const int il = t >> 2, cq = (t & 3) * 16;
#pragma unroll
    for (int k = 0; k < 4; ++k) {
      float4 v = *(const float4*)&Wh[(size_t)(i0 + il) * 256 + c0 + cq + k * 4];
      T[cq + k * 4 + 0][il] = f2bf(v.x);
      T[cq + k * 4 + 1][il] = f2bf(v.y);
      T[cq + k * 4 + 2][il] = f2bf(v.z);
      T[cq + k * 4 + 3][il] = f2bf(v.w);
    }
  }
  __syncthreads();
  {
    const int cl = t >> 2, iq = (t & 3) * 16;
    *(uint4*)&WhT[(size_t)(c0 + cl) * 8192 + i0 + iq]     = *(const uint4*)&T[cl][iq];
    *(uint4*)&WhT[(size_t)(c0 + cl) * 8192 + i0 + iq + 8] = *(const uint4*)&T[cl][iq + 8];
  }
}

// ---------------- Kernel Bmax: F2max = max_j f2[j] --------------------------
__global__ __launch_bounds__(256) void f2max_k(const float* __restrict__ f2,
                                               float* __restrict__ f2maxp) {
  __shared__ float red[256];
  const int t = threadIdx.x;
  float m = -1e30f;
  for (int c = 0; c < 32; c++) m = fmaxf(m, f2[c * 256 + t]);
  red[t] = m;
  __syncthreads();
  for (int s = 128; s; s >>= 1) {
    if (t < s) red[t] = fmaxf(red[t], red[t + s]);
    __syncthreads();
  }
  if (t == 0) f2maxp[0] = red[0];
}

// ---------------- Kernel M: pack adj>0 into a bitmask (8 MB) ----------------
__global__ __launch_bounds__(256) void maskpack(const int* __restrict__ adj,
                                                unsigned long long* __restrict__ mask) {
  __shared__ unsigned long long mbuf[4][128];
  const int t = threadIdx.x, wave = t >> 6, lane = t & 63;
  const int row = blockIdx.x * 4 + wave;
  const int* ap = adj + (size_t)row * 8192 + lane;
#pragma unroll 1
  for (int it0 = 0; it0 < 128; it0 += 4) {
    int a0 = ap[(it0 + 0) * 64];
    int a1 = ap[(it0 + 1) * 64];
    int a2 = ap[(it0 + 2) * 64];
    int a3 = ap[(it0 + 3) * 64];
    unsigned long long b0 = __ballot(a0 > 0);
    unsigned long long b1 = __ballot(a1 > 0);
    unsigned long long b2 = __ballot(a2 > 0);
    unsigned long long b3 = __ballot(a3 > 0);
    if (lane == 0) {
      mbuf[wave][it0 + 0] = b0; mbuf[wave][it0 + 1] = b1;
      mbuf[wave][it0 + 2] = b2; mbuf[wave][it0 + 3] = b3;
    }
  }
  __syncthreads();
  uint4* dst = (uint4*)(mask + (size_t)blockIdx.x * 4 * 128);
  dst[t] = ((const uint4*)mbuf)[t];
}

// ---------------- Kernel C: fused masked-softmax @ Wh -----------------------
// HYBRID split INSIDE the proven envelope: 256 threads, 4 waves =
// 2 col-groups (cg) x 2 j-halves (jh). Wave (cg,jh): output cols
// cg*128..cg*128+127 (4 MFMA tiles), j-range jh*4096..jh*4096+4095
// (256 steps of 16 j). P-compute duplicated only x2 (vs r6's x4);
// 4 bf loads/wave/step -> 16KB/step/CU line footprint (fits L1, step-pair
// line reuse). j-half partials combined in LDS (66.5 KB, r5 pattern).
// Config envelope: 256 thr + <=133KB LDS + grid 256 -- all previously passing.
#define ATTN_SUB(KSUB, MWORD, UCA, UCB, BFC, BFN, SCUR)                          \
  {                                                                              \
    const unsigned mbyte_ = ((MWORD) >> (((KSUB) & 1) * 16 + aselsh)) & 0xFFu;   \
    const unsigned uu_[8] = {UCA.x, UCA.y, UCA.z, UCA.w, UCB.x, UCB.y, UCB.z, UCB.w}; \
    float w_[8];                                                                 \
    _Pragma("unroll")                                                            \
    for (int jj = 0; jj < 8; jj++) {                                             \
      union { unsigned u; float f; } cu_, cv_;                                   \
      cu_.u = uu_[jj] << 16;                                                     \
      cv_.u = uu_[jj] & 0xFFFF0000u;                                             \
      float wv_ = (cu_.f > Ui) ? Ai * cu_.f : Bi * cv_.f;                        \
      int ext_ = ((int)(mbyte_ << (31 - jj))) >> 31;   /* bit -> 0 / all-ones */ \
      union { float f; int i; } wu_; wu_.f = wv_; wu_.i &= ext_;                 \
      w_[jj] = wu_.f;                                                            \
    }                                                                            \
    lpriv += ((w_[0] + w_[1]) + (w_[2] + w_[3])) + ((w_[4] + w_[5]) + (w_[6] + w_[7])); \
    union { uint4 q; short8 s; } af_;                                            \
    asm("v_cvt_pk_bf16_f32 %0, %1, %2" : "=v"(af_.q.x) : "v"(w_[0]), "v"(w_[1]));\
    asm("v_cvt_pk_bf16_f32 %0, %1, %2" : "=v"(af_.q.y) : "v"(w_[2]), "v"(w_[3]));\
    asm("v_cvt_pk_bf16_f32 %0, %1, %2" : "=v"(af_.q.z) : "v"(w_[4]), "v"(w_[5]));\
    asm("v_cvt_pk_bf16_f32 %0, %1, %2" : "=v"(af_.q.w) : "v"(w_[6]), "v"(w_[7]));\
    const int sn_ = (SCUR) + 1 < 256 ? (SCUR) + 1 : 255;                         \
    BFN[0] = *(const short8*)(wtp0 + (size_t)0 * (32 * 8192) + (size_t)sn_ * 16);\
    BFN[1] = *(const short8*)(wtp0 + (size_t)1 * (32 * 8192) + (size_t)sn_ * 16);\
    BFN[2] = *(const short8*)(wtp0 + (size_t)2 * (32 * 8192) + (size_t)sn_ * 16);\
    BFN[3] = *(const short8*)(wtp0 + (size_t)3 * (32 * 8192) + (size_t)sn_ * 16);\
    acc[0] = __builtin_amdgcn_mfma_f32_32x32x16_bf16(af_.s, BFC[0], acc[0], 0, 0, 0); \
    acc[1] = __builtin_amdgcn_mfma_f32_32x32x16_bf16(af_.s, BFC[1], acc[1], 0, 0, 0); \
    acc[2] = __builtin_amdgcn_mfma_f32_32x32x16_bf16(af_.s, BFC[2], acc[2], 0, 0, 0); \
    acc[3] = __builtin_amdgcn_mfma_f32_32x32x16_bf16(af_.s, BFC[3], acc[3], 0, 0, 0); \
  }

#define ATTN_GROUP(G, UC, UN, MC, MN)                                            \
  {                                                                              \
    const int gn_ = (G) < 63 ? (G) + 1 : 63;                                     \
    MN = mp[gn_];                                                                \
    UN[0] = *(const uint4*)(uvp + gn_ * 64 + 0);                                 \
    UN[1] = *(const uint4*)(uvp + gn_ * 64 + 4);                                 \
    ATTN_SUB(0, MC.x, UC[0], UC[1], bfA, bfB, 4 * (G) + 0);                      \
    UN[2] = *(const uint4*)(uvp + gn_ * 64 + 16);                                \
    UN[3] = *(const uint4*)(uvp + gn_ * 64 + 20);                                \
    ATTN_SUB(1, MC.x, UC[2], UC[3], bfB, bfA, 4 * (G) + 1);                      \
    UN[4] = *(const uint4*)(uvp + gn_ * 64 + 32);                                \
    UN[5] = *(const uint4*)(uvp + gn_ * 64 + 36);                                \
    ATTN_SUB(2, MC.y, UC[4], UC[5], bfA, bfB, 4 * (G) + 2);                      \
    UN[6] = *(const uint4*)(uvp + gn_ * 64 + 48);                                \
    UN[7] = *(const uint4*)(uvp + gn_ * 64 + 52);                                \
    ATTN_SUB(3, MC.y, UC[6], UC[7], bfB, bfA, 4 * (G) + 3);                      \
  }

__global__ __launch_bounds__(256, 1) void attn_main(const unsigned long long* __restrict__ maskw,
                                                    const float* __restrict__ f1,
                                                    const unsigned* __restrict__ uvpack,
                                                    const unsigned short* __restrict__ WhT,
                                                    const float* __restrict__ f2maxp,
                                                    float* __restrict__ out) {
  __shared__ float red[2][32][260];   // 66.5 KB; 260-float stride
  __shared__ float lsum[2][32];
  const int t = threadIdx.x;
  const int wave = t >> 6, lane = t & 63;
  const int cg = wave >> 1, jh = wave & 1;
  const int am = lane & 31, asel = lane >> 5;
  const int aselsh = asel * 8;
  const int r0 = blockIdx.x * 32;
  const int row = r0 + am;

  const float F2max = f2maxp[0];
  const float f1v = f1[row];
  const float x = f1v + F2max;
  const float M = x > 0.f ? x : ALPHA * x;   // analytic per-row max bound
  const float Ai = __expf(f1v - M);
  const float Bi = __expf(ALPHA * f1v - M);
  const float Ui = __expf(-f1v);             // u_j > Ui  <=>  f1_i + f2_j > 0

  f32x16 acc[4] = {};
  // streams for this wave's (cg, jh):
  const uint2* mp = (const uint2*)maskw + (size_t)row * 128 + jh * 64;
  const unsigned* uvp = uvpack + jh * 4096 + aselsh;
  const unsigned short* wtp0 = WhT + (size_t)(cg * 128 + am) * 8192 + jh * 4096 + aselsh;

  // prologue: group-0 mask+uv, step-0 B-fragments
  uint2 mg = mp[0], mgN;
  uint4 ug[8], ugN[8];
#pragma unroll
  for (int k = 0; k < 4; k++) {
    ug[2 * k]     = *(const uint4*)(uvp + k * 16);
    ug[2 * k + 1] = *(const uint4*)(uvp + k * 16 + 4);
  }
  short8 bfA[4], bfB[4];
#pragma unroll
  for (int ct = 0; ct < 4; ct++)
    bfA[ct] = *(const short8*)(wtp0 + (size_t)ct * (32 * 8192));
  float lpriv = 0.f;

#pragma unroll 1
  for (int gg = 0; gg < 32; ++gg) {
    ATTN_GROUP(2 * gg,     ug,  ugN, mg,  mgN);
    ATTN_GROUP(2 * gg + 1, ugN, ug,  mgN, mg);
  }

  // dump partials to LDS: jh slices summed later; cg pair writes disjoint cols
#pragma unroll
  for (int ct = 0; ct < 4; ct++) {
#pragma unroll
    for (int reg = 0; reg < 16; reg++) {
      const int rowl = (reg & 3) + 8 * (reg >> 2) + 4 * asel;  // verified C/D map
      red[jh][rowl][cg * 128 + ct * 32 + am] = acc[ct][reg];
    }
  }
  lpriv += __shfl_xor(lpriv, 32);      // combine asel halves of row am
  if (cg == 0 && asel == 0) lsum[jh][am] = lpriv;
  __syncthreads();

  // combine 2 j-halves, normalize, ELU, store out. 256 threads:
  // row rr = t>>3, col chunk (t&7)*32 (r5 epilogue pattern).
  const int rr = t >> 3, cb = (t & 7) * 32;
  const float l = lsum[0][rr] + lsum[1][rr];
  const float inv = 1.0f / fmaxf(l, 1e-30f);
#pragma unroll
  for (int cc = 0; cc < 32; cc += 4) {
    float4 v;
    v.x = red[0][rr][cb + cc + 0] + red[1][rr][cb + cc + 0];
    v.y = red[0][rr][cb + cc + 1] + red[1][rr][cb + cc + 1];
    v.z = red[0][rr][cb + cc + 2] + red[1][rr][cb + cc + 2];
    v.w = red[0][rr][cb + cc + 3] + red[1][rr][cb + cc + 3];
    v.x *= inv; v.y *= inv; v.z *= inv; v.w *= inv;
    float4 o;
    o.x = v.x > 0.f ? v.x : __expf(v.x) - 1.f;
    o.y = v.y > 0.f ? v.y : __expf(v.y) - 1.f;
    o.z = v.z > 0.f ? v.z : __expf(v.z) - 1.f;
    o.w = v.w > 0.f ? v.w : __expf(v.w) - 1.f;
    *(float4*)&out[(size_t)(r0 + rr) * 256 + cb + cc] = o;
  }
}

extern "C" void kernel_launch(void* const* d_in, const int* in_sizes, int n_in,
                              void* d_out, int out_size, void* d_ws, size_t ws_size,
                              hipStream_t stream) {
  const float* h  = (const float*)d_in[0];
  const int* adj  = (const int*)d_in[1];
  const float* W  = (const float*)d_in[2];
  const float* a  = (const float*)d_in[3];
  float* out = (float*)d_out;
  char* ws = (char*)d_ws;

  // ws layout:
  //  [0, 8M):    Wh fp32
  //  [8M, 16M):  mask bits (8 MB)
  //  [16M, 20M): WhT bf16 (4 MB)
  //  [20M ...):  f1 (32K), f2 (32K), uvpack (32K), f2max (128B)
  float* Wh            = (float*)ws;
  unsigned long long* mask = (unsigned long long*)(ws + (size_t)(8u << 20));
  unsigned short* WhT  = (unsigned short*)(ws + (size_t)(16u << 20));
  float* f1            = (float*)(ws + (size_t)(20u << 20));
  float* f2            = (float*)(ws + (size_t)(20u << 20) + (32u << 10));
  unsigned* uvpack     = (unsigned*)(ws + (size_t)(20u << 20) + (64u << 10));
  float* f2maxp        = (float*)(ws + (size_t)(20u << 20) + (96u << 10));

  maskpack<<<2048, 256, 0, stream>>>(adj, mask);
  gemm1<<<512, 256, 0, stream>>>(h, W, Wh);
  rowstats<<<2048, 256, 0, stream>>>(Wh, a, f1, f2, uvpack);
  wtrans<<<512, 256, 0, stream>>>(Wh, WhT);
  f2max_k<<<1, 256, 0, stream>>>(f2, f2maxp);
  attn_main<<<256, 256, 0, stream>>>(mask, f1, uvpack, WhT, f2maxp, out);
}

// Round 11
// 552.593 us; speedup vs baseline: 1.1248x; 1.0040x over previous
//
#include <hip/hip_runtime.h>
#include <cstdint>
#include <cstddef>

#define ALPHA 0.2f
// N=8192, Fin=512, Fout=256 hard-coded per problem instance.

typedef __attribute__((ext_vector_type(8)))  short short8;   // 8 bf16 (4 VGPRs)
typedef __attribute__((ext_vector_type(16))) float f32x16;   // 32x32 MFMA acc

static __device__ __forceinline__ unsigned short f2bf(float x) {
  union { float f; unsigned u; } c; c.f = x;
  unsigned u = c.u;
  unsigned r = (u + 0x7FFFu + ((u >> 16) & 1u)) >> 16;  // RNE
  return (unsigned short)r;
}

// ---------------- Kernel A: Wh = h @ W  (fp32, 8192x512 * 512x256) ----------
// r9 tile (passed): BM=64, BN=64, BK=32, 256 threads, 4x4/thread,
// grid 512 = 2 blocks/CU.
__global__ __launch_bounds__(256, 2) void gemm1(const float* __restrict__ h,
                                                const float* __restrict__ W,
                                                float* __restrict__ Wh) {
  __shared__ float As[32][68];   // [k][m], padded
  __shared__ float Bs[32][64];   // [k][n]
  const int t = threadIdx.x;
  const int bid = blockIdx.x;
  const int nb = bid & 3, mb = bid >> 2;
  const int m0 = mb * 64, n0 = nb * 64;
  const int ty = t >> 4, tx = t & 15;   // rows ty*4.., cols tx*4..
  float acc[4][4];
#pragma unroll
  for (int i = 0; i < 4; i++)
#pragma unroll
    for (int j = 0; j < 4; j++) acc[i][j] = 0.f;

  for (int k0 = 0; k0 < 512; k0 += 32) {
#pragma unroll
    for (int c = 0; c < 2; c++) {                 // stage A with transpose
      int m = c * 32 + (t >> 3);
      int kq = (t & 7) * 4;
      float4 v = *(const float4*)&h[(size_t)(m0 + m) * 512 + k0 + kq];
      As[kq + 0][m] = v.x; As[kq + 1][m] = v.y;
      As[kq + 2][m] = v.z; As[kq + 3][m] = v.w;
    }
#pragma unroll
    for (int c = 0; c < 2; c++) {                 // stage B
      int k = c * 16 + (t >> 4);
      int n = (t & 15) * 4;
      *(float4*)&Bs[k][n] = *(const float4*)&W[(size_t)(k0 + k) * 256 + n0 + n];
    }
    __syncthreads();
#pragma unroll
    for (int k = 0; k < 32; k++) {
      float4 a = *(float4*)&As[k][ty * 4];
      float4 b = *(float4*)&Bs[k][tx * 4];
      float av[4] = {a.x, a.y, a.z, a.w};
      float bv[4] = {b.x, b.y, b.z, b.w};
#pragma unroll
      for (int i = 0; i < 4; i++)
#pragma unroll
        for (int j = 0; j < 4; j++) acc[i][j] = fmaf(av[i], bv[j], acc[i][j]);
    }
    __syncthreads();
  }
#pragma unroll
  for (int i = 0; i < 4; i++) {
    float4 v = {acc[i][0], acc[i][1], acc[i][2], acc[i][3]};
    *(float4*)&Wh[(size_t)(m0 + ty * 4 + i) * 256 + n0 + tx * 4] = v;
  }
}

// ------------- Kernel B: per-row f1,f2 and u/v pack (verbatim) --------------
__global__ __launch_bounds__(256) void rowstats(const float* __restrict__ Wh,
                                                const float* __restrict__ a,
                                                float* __restrict__ f1,
                                                float* __restrict__ f2,
                                                unsigned* __restrict__ uvpack) {
  const int t = threadIdx.x;
  const int w = t >> 6, lane = t & 63;
  const int i = blockIdx.x * 4 + w;
  float4 wv = *(const float4*)&Wh[(size_t)i * 256 + lane * 4];
  float4 a1 = *(const float4*)&a[lane * 4];
  float4 a2 = *(const float4*)&a[256 + lane * 4];
  float s1 = wv.x * a1.x + wv.y * a1.y + wv.z * a1.z + wv.w * a1.w;
  float s2 = wv.x * a2.x + wv.y * a2.y + wv.z * a2.z + wv.w * a2.w;
#pragma unroll
  for (int off = 32; off; off >>= 1) { s1 += __shfl_xor(s1, off); s2 += __shfl_xor(s2, off); }
  if (lane == 0) {
    f1[i] = s1; f2[i] = s2;
    float u = __expf(s2), v = __expf(ALPHA * s2);
    uvpack[i] = (unsigned)f2bf(u) | ((unsigned)f2bf(v) << 16);
  }
}

// ------------- Kernel B2: LDS-tiled transpose (verbatim) --------------------
__global__ __launch_bounds__(256) void wtrans(const float* __restrict__ Wh,
                                              unsigned short* __restrict__ WhT) {
  __shared__ unsigned short T[64][80];   // 80-short stride
  const int t = threadIdx.x;
  const int bi = blockIdx.x & 127;
  const int bc = blockIdx.x >> 7;
  const int i0 = bi * 64, c0 = bc * 64;
  {
    const int il = t >> 2, cq = (t & 3) * 16;
#pragma unroll
    for (int k = 0; k < 4; ++k) {
      float4 v = *(const float4*)&Wh[(size_t)(i0 + il) * 256 + c0 + cq + k * 4];
      T[cq + k * 4 + 0][il] = f2bf(v.x);
      T[cq + k * 4 + 1][il] = f2bf(v.y);
      T[cq + k * 4 + 2][il] = f2bf(v.z);
      T[cq + k * 4 + 3][il] = f2bf(v.w);
    }
  }
  __syncthreads();
  {
    const int cl = t >> 2, iq = (t & 3) * 16;
    *(uint4*)&WhT[(size_t)(c0 + cl) * 8192 + i0 + iq]     = *(const uint4*)&T[cl][iq];
    *(uint4*)&WhT[(size_t)(c0 + cl) * 8192 + i0 + iq + 8] = *(const uint4*)&T[cl][iq + 8];
  }
}

// ---------------- Kernel Bmax: F2max = max_j f2[j] --------------------------
__global__ __launch_bounds__(256) void f2max_k(const float* __restrict__ f2,
                                               float* __restrict__ f2maxp) {
  __shared__ float red[256];
  const int t = threadIdx.x;
  float m = -1e30f;
  for (int c = 0; c < 32; c++) m = fmaxf(m, f2[c * 256 + t]);
  red[t] = m;
  __syncthreads();
  for (int s = 128; s; s >>= 1) {
    if (t < s) red[t] = fmaxf(red[t], red[t + s]);
    __syncthreads();
  }
  if (t == 0) f2maxp[0] = red[0];
}

// ---------------- Kernel M: pack adj>0 into a bitmask (8 MB) ----------------
__global__ __launch_bounds__(256) void maskpack(const int* __restrict__ adj,
                                                unsigned long long* __restrict__ mask) {
  __shared__ unsigned long long mbuf[4][128];
  const int t = threadIdx.x, wave = t >> 6, lane = t & 63;
  const int row = blockIdx.x * 4 + wave;
  const int* ap = adj + (size_t)row * 8192 + lane;
#pragma unroll 1
  for (int it0 = 0; it0 < 128; it0 += 4) {
    int a0 = ap[(it0 + 0) * 64];
    int a1 = ap[(it0 + 1) * 64];
    int a2 = ap[(it0 + 2) * 64];
    int a3 = ap[(it0 + 3) * 64];
    unsigned long long b0 = __ballot(a0 > 0);
    unsigned long long b1 = __ballot(a1 > 0);
    unsigned long long b2 = __ballot(a2 > 0);
    unsigned long long b3 = __ballot(a3 > 0);
    if (lane == 0) {
      mbuf[wave][it0 + 0] = b0; mbuf[wave][it0 + 1] = b1;
      mbuf[wave][it0 + 2] = b2; mbuf[wave][it0 + 3] = b3;
    }
  }
  __syncthreads();
  uint4* dst = (uint4*)(mask + (size_t)blockIdx.x * 4 * 128);
  dst[t] = ((const uint4*)mbuf)[t];
}

// ---------------- Kernel C: fused masked-softmax @ Wh -----------------------
// CG-BLOCK split, BISECT: identical to round-10 source except
// __launch_bounds__(256, 1) (round-9's directive) instead of (256, 2).
// Occupancy is a scheduler decision: grid 512, 68KB LDS -> 2 blocks/CU
// naturally (136KB < 160KB, ~92 VGPR), so the TLP thesis is still tested.
#define ATTN_SUB(KSUB, MWORD, UCA, UCB, BFC, BFN, SCUR)                          \
  {                                                                              \
    const unsigned mbyte_ = ((MWORD) >> (((KSUB) & 1) * 16 + aselsh)) & 0xFFu;   \
    const unsigned uu_[8] = {UCA.x, UCA.y, UCA.z, UCA.w, UCB.x, UCB.y, UCB.z, UCB.w}; \
    float w_[8];                                                                 \
    _Pragma("unroll")                                                            \
    for (int jj = 0; jj < 8; jj++) {                                             \
      union { unsigned u; float f; } cu_, cv_;                                   \
      cu_.u = uu_[jj] << 16;                                                     \
      cv_.u = uu_[jj] & 0xFFFF0000u;                                             \
      float wv_ = (cu_.f > Ui) ? Ai * cu_.f : Bi * cv_.f;                        \
      int ext_ = ((int)(mbyte_ << (31 - jj))) >> 31;   /* bit -> 0 / all-ones */ \
      union { float f; int i; } wu_; wu_.f = wv_; wu_.i &= ext_;                 \
      w_[jj] = wu_.f;                                                            \
    }                                                                            \
    lpriv += ((w_[0] + w_[1]) + (w_[2] + w_[3])) + ((w_[4] + w_[5]) + (w_[6] + w_[7])); \
    union { uint4 q; short8 s; } af_;                                            \
    asm("v_cvt_pk_bf16_f32 %0, %1, %2" : "=v"(af_.q.x) : "v"(w_[0]), "v"(w_[1]));\
    asm("v_cvt_pk_bf16_f32 %0, %1, %2" : "=v"(af_.q.y) : "v"(w_[2]), "v"(w_[3]));\
    asm("v_cvt_pk_bf16_f32 %0, %1, %2" : "=v"(af_.q.z) : "v"(w_[4]), "v"(w_[5]));\
    asm("v_cvt_pk_bf16_f32 %0, %1, %2" : "=v"(af_.q.w) : "v"(w_[6]), "v"(w_[7]));\
    const int sn_ = (SCUR) + 1 < 128 ? (SCUR) + 1 : 127;                         \
    BFN[0] = *(const short8*)(wtp0 + (size_t)0 * (32 * 8192) + (size_t)sn_ * 16);\
    BFN[1] = *(const short8*)(wtp0 + (size_t)1 * (32 * 8192) + (size_t)sn_ * 16);\
    BFN[2] = *(const short8*)(wtp0 + (size_t)2 * (32 * 8192) + (size_t)sn_ * 16);\
    BFN[3] = *(const short8*)(wtp0 + (size_t)3 * (32 * 8192) + (size_t)sn_ * 16);\
    acc[0] = __builtin_amdgcn_mfma_f32_32x32x16_bf16(af_.s, BFC[0], acc[0], 0, 0, 0); \
    acc[1] = __builtin_amdgcn_mfma_f32_32x32x16_bf16(af_.s, BFC[1], acc[1], 0, 0, 0); \
    acc[2] = __builtin_amdgcn_mfma_f32_32x32x16_bf16(af_.s, BFC[2], acc[2], 0, 0, 0); \
    acc[3] = __builtin_amdgcn_mfma_f32_32x32x16_bf16(af_.s, BFC[3], acc[3], 0, 0, 0); \
  }

#define ATTN_GROUP(G, UC, UN, MC, MN)                                            \
  {                                                                              \
    const int gn_ = (G) < 31 ? (G) + 1 : 31;                                     \
    MN = mp[gn_];                                                                \
    UN[0] = *(const uint4*)(uvp + gn_ * 64 + 0);                                 \
    UN[1] = *(const uint4*)(uvp + gn_ * 64 + 4);                                 \
    ATTN_SUB(0, MC.x, UC[0], UC[1], bfA, bfB, 4 * (G) + 0);                      \
    UN[2] = *(const uint4*)(uvp + gn_ * 64 + 16);                                \
    UN[3] = *(const uint4*)(uvp + gn_ * 64 + 20);                                \
    ATTN_SUB(1, MC.x, UC[2], UC[3], bfB, bfA, 4 * (G) + 1);                      \
    UN[4] = *(const uint4*)(uvp + gn_ * 64 + 32);                                \
    UN[5] = *(const uint4*)(uvp + gn_ * 64 + 36);                                \
    ATTN_SUB(2, MC.y, UC[4], UC[5], bfA, bfB, 4 * (G) + 2);                      \
    UN[6] = *(const uint4*)(uvp + gn_ * 64 + 48);                                \
    UN[7] = *(const uint4*)(uvp + gn_ * 64 + 52);                                \
    ATTN_SUB(3, MC.y, UC[6], UC[7], bfB, bfA, 4 * (G) + 3);                      \
  }

__global__ __launch_bounds__(256, 1) void attn_main(const unsigned long long* __restrict__ maskw,
                                                    const float* __restrict__ f1,
                                                    const unsigned* __restrict__ uvpack,
                                                    const unsigned short* __restrict__ WhT,
                                                    const float* __restrict__ f2maxp,
                                                    float* __restrict__ out) {
  __shared__ float red[4][32][132];   // 4 jq x 32 rows x 128 cols (+4 pad); 67.6 KB
  __shared__ float lsum[4][32];
  const int t = threadIdx.x;
  const int wave = t >> 6, lane = t & 63;
  const int jq = wave;                  // each wave owns a j-quarter
  const int am = lane & 31, asel = lane >> 5;
  const int aselsh = asel * 8;
  const int bid = blockIdx.x;
  const int cg = bid & 1;               // col-group from block
  const int r0 = (bid >> 1) * 32;
  const int row = r0 + am;

  const float F2max = f2maxp[0];
  const float f1v = f1[row];
  const float x = f1v + F2max;
  const float M = x > 0.f ? x : ALPHA * x;   // analytic per-row max bound
  const float Ai = __expf(f1v - M);
  const float Bi = __expf(ALPHA * f1v - M);
  const float Ui = __expf(-f1v);             // u_j > Ui  <=>  f1_i + f2_j > 0

  f32x16 acc[4] = {};
  // streams for this wave's jq (block-wide cg):
  const uint2* mp = (const uint2*)maskw + (size_t)row * 128 + jq * 32;
  const unsigned* uvp = uvpack + jq * 2048 + aselsh;
  const unsigned short* wtp0 = WhT + (size_t)(cg * 128 + am) * 8192 + jq * 2048 + aselsh;

  // prologue: group-0 mask+uv, step-0 B-fragments
  uint2 mg = mp[0], mgN;
  uint4 ug[8], ugN[8];
#pragma unroll
  for (int k = 0; k < 4; k++) {
    ug[2 * k]     = *(const uint4*)(uvp + k * 16);
    ug[2 * k + 1] = *(const uint4*)(uvp + k * 16 + 4);
  }
  short8 bfA[4], bfB[4];
#pragma unroll
  for (int ct = 0; ct < 4; ct++)
    bfA[ct] = *(const short8*)(wtp0 + (size_t)ct * (32 * 8192));
  float lpriv = 0.f;

#pragma unroll 1
  for (int gg = 0; gg < 16; ++gg) {
    ATTN_GROUP(2 * gg,     ug,  ugN, mg,  mgN);
    ATTN_GROUP(2 * gg + 1, ugN, ug,  mgN, mg);
  }

  // dump partials to LDS (each wave its own jq slice)
#pragma unroll
  for (int ct = 0; ct < 4; ct++) {
#pragma unroll
    for (int reg = 0; reg < 16; reg++) {
      const int rowl = (reg & 3) + 8 * (reg >> 2) + 4 * asel;  // verified C/D map
      red[jq][rowl][ct * 32 + am] = acc[ct][reg];
    }
  }
  lpriv += __shfl_xor(lpriv, 32);      // combine asel halves of row am
  if (asel == 0) lsum[jq][am] = lpriv;
  __syncthreads();

  // combine 4 j-quarters, normalize, ELU, store this block's 128-col slice.
  // 256 threads: row rr = t>>3, col chunk (t&7)*16 within the slice.
  const int rr = t >> 3, cb = (t & 7) * 16;
  const float l = lsum[0][rr] + lsum[1][rr] + lsum[2][rr] + lsum[3][rr];
  const float inv = 1.0f / fmaxf(l, 1e-30f);
#pragma unroll
  for (int cc = 0; cc < 16; cc += 4) {
    float4 v;
    v.x = red[0][rr][cb + cc + 0] + red[1][rr][cb + cc + 0] + red[2][rr][cb + cc + 0] + red[3][rr][cb + cc + 0];
    v.y = red[0][rr][cb + cc + 1] + red[1][rr][cb + cc + 1] + red[2][rr][cb + cc + 1] + red[3][rr][cb + cc + 1];
    v.z = red[0][rr][cb + cc + 2] + red[1][rr][cb + cc + 2] + red[2][rr][cb + cc + 2] + red[3][rr][cb + cc + 2];
    v.w = red[0][rr][cb + cc + 3] + red[1][rr][cb + cc + 3] + red[2][rr][cb + cc + 3] + red[3][rr][cb + cc + 3];
    v.x *= inv; v.y *= inv; v.z *= inv; v.w *= inv;
    float4 o;
    o.x = v.x > 0.f ? v.x : __expf(v.x) - 1.f;
    o.y = v.y > 0.f ? v.y : __expf(v.y) - 1.f;
    o.z = v.z > 0.f ? v.z : __expf(v.z) - 1.f;
    o.w = v.w > 0.f ? v.w : __expf(v.w) - 1.f;
    *(float4*)&out[(size_t)(r0 + rr) * 256 + cg * 128 + cb + cc] = o;
  }
}

extern "C" void kernel_launch(void* const* d_in, const int* in_sizes, int n_in,
                              void* d_out, int out_size, void* d_ws, size_t ws_size,
                              hipStream_t stream) {
  const float* h  = (const float*)d_in[0];
  const int* adj  = (const int*)d_in[1];
  const float* W  = (const float*)d_in[2];
  const float* a  = (const float*)d_in[3];
  float* out = (float*)d_out;
  char* ws = (char*)d_ws;

  // ws layout:
  //  [0, 8M):    Wh fp32
  //  [8M, 16M):  mask bits (8 MB)
  //  [16M, 20M): WhT bf16 (4 MB)
  //  [20M ...):  f1 (32K), f2 (32K), uvpack (32K), f2max (128B)
  float* Wh            = (float*)ws;
  unsigned long long* mask = (unsigned long long*)(ws + (size_t)(8u << 20));
  unsigned short* WhT  = (unsigned short*)(ws + (size_t)(16u << 20));
  float* f1            = (float*)(ws + (size_t)(20u << 20));
  float* f2            = (float*)(ws + (size_t)(20u << 20) + (32u << 10));
  unsigned* uvpack     = (unsigned*)(ws + (size_t)(20u << 20) + (64u << 10));
  float* f2maxp        = (float*)(ws + (size_t)(20u << 20) + (96u << 10));

  maskpack<<<2048, 256, 0, stream>>>(adj, mask);
  gemm1<<<512, 256, 0, stream>>>(h, W, Wh);
  rowstats<<<2048, 256, 0, stream>>>(Wh, a, f1, f2, uvpack);
  wtrans<<<512, 256, 0, stream>>>(Wh, WhT);
  f2max_k<<<1, 256, 0, stream>>>(f2, f2maxp);
  attn_main<<<512, 256, 0, stream>>>(mask, f1, uvpack, WhT, f2maxp, out);
}

// Round 12
// 537.450 us; speedup vs baseline: 1.1565x; 1.0282x over previous
//
#include <hip/hip_runtime.h>
#include <cstdint>
#include <cstddef>

#define ALPHA 0.2f
// N=8192, Fin=512, Fout=256 hard-coded per problem instance.

typedef __attribute__((ext_vector_type(8)))  short short8;   // 8 bf16 (4 VGPRs)
typedef __attribute__((ext_vector_type(16))) float f32x16;   // 32x32 MFMA acc

static __device__ __forceinline__ unsigned short f2bf(float x) {
  union { float f; unsigned u; } c; c.f = x;
  unsigned u = c.u;
  unsigned r = (u + 0x7FFFu + ((u >> 16) & 1u)) >> 16;  // RNE
  return (unsigned short)r;
}

// ------------- Kernel A+M merged: maskpack (2048 blks) || gemm1 (512 blks) --
// maskpack is HBM-BW-bound, gemm1 is VALU/LDS-latency-bound -> co-residency
// overlaps them (total ~= max, not sum). Interleaved mapping: bid%5==0 ->
// gemm block gemm_id=bid/5 (512 of 2560); else mask_id = bid - bid/5 - 1
// (0..2047, bijective). Both code paths verbatim from passing kernels;
// barriers are per-block-uniform. LDS = As+Bs+mbuf = 21KB -> 2 blocks/CU.
__global__ __launch_bounds__(256, 2) void maskgemm(const int* __restrict__ adj,
                                                   unsigned long long* __restrict__ mask,
                                                   const float* __restrict__ h,
                                                   const float* __restrict__ W,
                                                   float* __restrict__ Wh) {
  __shared__ float As[32][68];   // [k][m], padded (gemm path)
  __shared__ float Bs[32][64];   // [k][n]   (gemm path)
  __shared__ unsigned long long mbuf[4][128];  // (mask path)
  const int t = threadIdx.x;
  const int b = blockIdx.x;
  if (b % 5 == 0) {
    // ---- gemm path (r9-verbatim tile: BM=64, BN=64, BK=32, 4x4/thread) ----
    const int bid = b / 5;
    const int nb = bid & 3, mb = bid >> 2;
    const int m0 = mb * 64, n0 = nb * 64;
    const int ty = t >> 4, tx = t & 15;
    float acc[4][4];
#pragma unroll
    for (int i = 0; i < 4; i++)
#pragma unroll
      for (int j = 0; j < 4; j++) acc[i][j] = 0.f;

    for (int k0 = 0; k0 < 512; k0 += 32) {
#pragma unroll
      for (int c = 0; c < 2; c++) {                 // stage A with transpose
        int m = c * 32 + (t >> 3);
        int kq = (t & 7) * 4;
        float4 v = *(const float4*)&h[(size_t)(m0 + m) * 512 + k0 + kq];
        As[kq + 0][m] = v.x; As[kq + 1][m] = v.y;
        As[kq + 2][m] = v.z; As[kq + 3][m] = v.w;
      }
#pragma unroll
      for (int c = 0; c < 2; c++) {                 // stage B
        int k = c * 16 + (t >> 4);
        int n = (t & 15) * 4;
        *(float4*)&Bs[k][n] = *(const float4*)&W[(size_t)(k0 + k) * 256 + n0 + n];
      }
      __syncthreads();
#pragma unroll
      for (int k = 0; k < 32; k++) {
        float4 a = *(float4*)&As[k][ty * 4];
        float4 bb = *(float4*)&Bs[k][tx * 4];
        float av[4] = {a.x, a.y, a.z, a.w};
        float bv[4] = {bb.x, bb.y, bb.z, bb.w};
#pragma unroll
        for (int i = 0; i < 4; i++)
#pragma unroll
          for (int j = 0; j < 4; j++) acc[i][j] = fmaf(av[i], bv[j], acc[i][j]);
      }
      __syncthreads();
    }
#pragma unroll
    for (int i = 0; i < 4; i++) {
      float4 v = {acc[i][0], acc[i][1], acc[i][2], acc[i][3]};
      *(float4*)&Wh[(size_t)(m0 + ty * 4 + i) * 256 + n0 + tx * 4] = v;
    }
  } else {
    // ---- maskpack path (verbatim) ----
    const int mask_id = b - b / 5 - 1;
    const int wave = t >> 6, lane = t & 63;
    const int row = mask_id * 4 + wave;
    const int* ap = adj + (size_t)row * 8192 + lane;
#pragma unroll 1
    for (int it0 = 0; it0 < 128; it0 += 4) {
      int a0 = ap[(it0 + 0) * 64];
      int a1 = ap[(it0 + 1) * 64];
      int a2 = ap[(it0 + 2) * 64];
      int a3 = ap[(it0 + 3) * 64];
      unsigned long long b0 = __ballot(a0 > 0);
      unsigned long long b1 = __ballot(a1 > 0);
      unsigned long long b2 = __ballot(a2 > 0);
      unsigned long long b3 = __ballot(a3 > 0);
      if (lane == 0) {
        mbuf[wave][it0 + 0] = b0; mbuf[wave][it0 + 1] = b1;
        mbuf[wave][it0 + 2] = b2; mbuf[wave][it0 + 3] = b3;
      }
    }
    __syncthreads();
    uint4* dst = (uint4*)(mask + (size_t)mask_id * 4 * 128);
    dst[t] = ((const uint4*)mbuf)[t];
  }
}

// ------------- Kernel B: per-row f1,f2 and u/v pack (verbatim) --------------
__global__ __launch_bounds__(256) void rowstats(const float* __restrict__ Wh,
                                                const float* __restrict__ a,
                                                float* __restrict__ f1,
                                                float* __restrict__ f2,
                                                unsigned* __restrict__ uvpack) {
  const int t = threadIdx.x;
  const int w = t >> 6, lane = t & 63;
  const int i = blockIdx.x * 4 + w;
  float4 wv = *(const float4*)&Wh[(size_t)i * 256 + lane * 4];
  float4 a1 = *(const float4*)&a[lane * 4];
  float4 a2 = *(const float4*)&a[256 + lane * 4];
  float s1 = wv.x * a1.x + wv.y * a1.y + wv.z * a1.z + wv.w * a1.w;
  float s2 = wv.x * a2.x + wv.y * a2.y + wv.z * a2.z + wv.w * a2.w;
#pragma unroll
  for (int off = 32; off; off >>= 1) { s1 += __shfl_xor(s1, off); s2 += __shfl_xor(s2, off); }
  if (lane == 0) {
    f1[i] = s1; f2[i] = s2;
    float u = __expf(s2), v = __expf(ALPHA * s2);
    uvpack[i] = (unsigned)f2bf(u) | ((unsigned)f2bf(v) << 16);
  }
}

// ------------- Kernel B2: LDS-tiled transpose (verbatim) --------------------
__global__ __launch_bounds__(256) void wtrans(const float* __restrict__ Wh,
                                              unsigned short* __restrict__ WhT) {
  __shared__ unsigned short T[64][80];   // 80-short stride
  const int t = threadIdx.x;
  const int bi = blockIdx.x & 127;
  const int bc = blockIdx.x >> 7;
  const int i0 = bi * 64, c0 = bc * 64;
  {
    const int il = t >> 2, cq = (t & 3) * 16;
#pragma unroll
    for (int k = 0; k < 4; ++k) {
      float4 v = *(const float4*)&Wh[(size_t)(i0 + il) * 256 + c0 + cq + k * 4];
      T[cq + k * 4 + 0][il] = f2bf(v.x);
      T[cq + k * 4 + 1][il] = f2bf(v.y);
      T[cq + k * 4 + 2][il] = f2bf(v.z);
      T[cq + k * 4 + 3][il] = f2bf(v.w);
    }
  }
  __syncthreads();
  {
    const int cl = t >> 2, iq = (t & 3) * 16;
    *(uint4*)&WhT[(size_t)(c0 + cl) * 8192 + i0 + iq]     = *(const uint4*)&T[cl][iq];
    *(uint4*)&WhT[(size_t)(c0 + cl) * 8192 + i0 + iq + 8] = *(const uint4*)&T[cl][iq + 8];
  }
}

// ---------------- Kernel Bmax: F2max = max_j f2[j] --------------------------
__global__ __launch_bounds__(256) void f2max_k(const float* __restrict__ f2,
                                               float* __restrict__ f2maxp) {
  __shared__ float red[256];
  const int t = threadIdx.x;
  float m = -1e30f;
  for (int c = 0; c < 32; c++) m = fmaxf(m, f2[c * 256 + t]);
  red[t] = m;
  __syncthreads();
  for (int s = 128; s; s >>= 1) {
    if (t < s) red[t] = fmaxf(red[t], red[t + s]);
    __syncthreads();
  }
  if (t == 0) f2maxp[0] = red[0];
}

// ---------------- Kernel C: fused masked-softmax @ Wh -----------------------
// r11 cg-block structure (passing) + QUAD-BUFFERED bf with PAIRED line loads:
// steps 2k/2k+1 read adjacent 16B halves of the same 64B WhT line (col byte
// offset s*32 + asel*16); issuing both back-to-back makes the 2nd a same-line
// hit and deepens prefetch to 2-3 steps (~2x the latency cover of r11's
// 1-step double buffer). Same addresses/MFMA order -> bit-identical output.
// KEEP __launch_bounds__(256,1): (256,2) on this kernel silently zeroes
// output (r10 vs r11 bisect). 2 blocks/CU comes from the scheduler
// (68KB LDS, ~140 VGPR).
#define LOADBF(BUF, SIDX)                                                        \
  {                                                                              \
    const int s_ = (SIDX) < 128 ? (SIDX) : 127;                                  \
    BUF[0] = *(const short8*)(wtp0 + (size_t)0 * (32 * 8192) + (size_t)s_ * 16); \
    BUF[1] = *(const short8*)(wtp0 + (size_t)1 * (32 * 8192) + (size_t)s_ * 16); \
    BUF[2] = *(const short8*)(wtp0 + (size_t)2 * (32 * 8192) + (size_t)s_ * 16); \
    BUF[3] = *(const short8*)(wtp0 + (size_t)3 * (32 * 8192) + (size_t)s_ * 16); \
  }

#define ATTN_SUB(KSUB, MWORD, UCA, UCB, BFC)                                     \
  {                                                                              \
    const unsigned mbyte_ = ((MWORD) >> (((KSUB) & 1) * 16 + aselsh)) & 0xFFu;   \
    const unsigned uu_[8] = {UCA.x, UCA.y, UCA.z, UCA.w, UCB.x, UCB.y, UCB.z, UCB.w}; \
    float w_[8];                                                                 \
    _Pragma("unroll")                                                            \
    for (int jj = 0; jj < 8; jj++) {                                             \
      union { unsigned u; float f; } cu_, cv_;                                   \
      cu_.u = uu_[jj] << 16;                                                     \
      cv_.u = uu_[jj] & 0xFFFF0000u;                                             \
      float wv_ = (cu_.f > Ui) ? Ai * cu_.f : Bi * cv_.f;                        \
      int ext_ = ((int)(mbyte_ << (31 - jj))) >> 31;   /* bit -> 0 / all-ones */ \
      union { float f; int i; } wu_; wu_.f = wv_; wu_.i &= ext_;                 \
      w_[jj] = wu_.f;                                                            \
    }                                                                            \
    lpriv += ((w_[0] + w_[1]) + (w_[2] + w_[3])) + ((w_[4] + w_[5]) + (w_[6] + w_[7])); \
    union { uint4 q; short8 s; } af_;                                            \
    asm("v_cvt_pk_bf16_f32 %0, %1, %2" : "=v"(af_.q.x) : "v"(w_[0]), "v"(w_[1]));\
    asm("v_cvt_pk_bf16_f32 %0, %1, %2" : "=v"(af_.q.y) : "v"(w_[2]), "v"(w_[3]));\
    asm("v_cvt_pk_bf16_f32 %0, %1, %2" : "=v"(af_.q.z) : "v"(w_[4]), "v"(w_[5]));\
    asm("v_cvt_pk_bf16_f32 %0, %1, %2" : "=v"(af_.q.w) : "v"(w_[6]), "v"(w_[7]));\
    acc[0] = __builtin_amdgcn_mfma_f32_32x32x16_bf16(af_.s, BFC[0], acc[0], 0, 0, 0); \
    acc[1] = __builtin_amdgcn_mfma_f32_32x32x16_bf16(af_.s, BFC[1], acc[1], 0, 0, 0); \
    acc[2] = __builtin_amdgcn_mfma_f32_32x32x16_bf16(af_.s, BFC[2], acc[2], 0, 0, 0); \
    acc[3] = __builtin_amdgcn_mfma_f32_32x32x16_bf16(af_.s, BFC[3], acc[3], 0, 0, 0); \
  }

#define ATTN_GROUP(G, UC, UN, MC, MN)                                            \
  {                                                                              \
    const int gn_ = (G) < 31 ? (G) + 1 : 31;                                     \
    MN = mp[gn_];                                                                \
    UN[0] = *(const uint4*)(uvp + gn_ * 64 + 0);                                 \
    UN[1] = *(const uint4*)(uvp + gn_ * 64 + 4);                                 \
    LOADBF(bfs2, 4 * (G) + 2);           /* paired: 4G+2,4G+3 share lines   */  \
    LOADBF(bfs3, 4 * (G) + 3);                                                   \
    ATTN_SUB(0, MC.x, UC[0], UC[1], bfs0);                                       \
    UN[2] = *(const uint4*)(uvp + gn_ * 64 + 16);                                \
    UN[3] = *(const uint4*)(uvp + gn_ * 64 + 20);                                \
    ATTN_SUB(1, MC.x, UC[2], UC[3], bfs1);                                       \
    UN[4] = *(const uint4*)(uvp + gn_ * 64 + 32);                                \
    UN[5] = *(const uint4*)(uvp + gn_ * 64 + 36);                                \
    LOADBF(bfs0, 4 * (G) + 4);           /* next group's first pair         */  \
    LOADBF(bfs1, 4 * (G) + 5);                                                   \
    ATTN_SUB(2, MC.y, UC[4], UC[5], bfs2);                                       \
    UN[6] = *(const uint4*)(uvp + gn_ * 64 + 48);                                \
    UN[7] = *(const uint4*)(uvp + gn_ * 64 + 52);                                \
    ATTN_SUB(3, MC.y, UC[6], UC[7], bfs3);                                       \
  }

__global__ __launch_bounds__(256, 1) void attn_main(const unsigned long long* __restrict__ maskw,
                                                    const float* __restrict__ f1,
                                                    const unsigned* __restrict__ uvpack,
                                                    const unsigned short* __restrict__ WhT,
                                                    const float* __restrict__ f2maxp,
                                                    float* __restrict__ out) {
  __shared__ float red[4][32][132];   // 4 jq x 32 rows x 128 cols (+4 pad); 67.6 KB
  __shared__ float lsum[4][32];
  const int t = threadIdx.x;
  const int wave = t >> 6, lane = t & 63;
  const int jq = wave;                  // each wave owns a j-quarter
  const int am = lane & 31, asel = lane >> 5;
  const int aselsh = asel * 8;
  const int bid = blockIdx.x;
  const int cg = bid & 1;               // col-group from block
  const int r0 = (bid >> 1) * 32;
  const int row = r0 + am;

  const float F2max = f2maxp[0];
  const float f1v = f1[row];
  const float x = f1v + F2max;
  const float M = x > 0.f ? x : ALPHA * x;   // analytic per-row max bound
  const float Ai = __expf(f1v - M);
  const float Bi = __expf(ALPHA * f1v - M);
  const float Ui = __expf(-f1v);             // u_j > Ui  <=>  f1_i + f2_j > 0

  f32x16 acc[4] = {};
  // streams for this wave's jq (block-wide cg):
  const uint2* mp = (const uint2*)maskw + (size_t)row * 128 + jq * 32;
  const unsigned* uvp = uvpack + jq * 2048 + aselsh;
  const unsigned short* wtp0 = WhT + (size_t)(cg * 128 + am) * 8192 + jq * 2048 + aselsh;

  // prologue: group-0 mask+uv; bf steps 0 and 1 (a line pair)
  uint2 mg = mp[0], mgN;
  uint4 ug[8], ugN[8];
#pragma unroll
  for (int k = 0; k < 4; k++) {
    ug[2 * k]     = *(const uint4*)(uvp + k * 16);
    ug[2 * k + 1] = *(const uint4*)(uvp + k * 16 + 4);
  }
  short8 bfs0[4], bfs1[4], bfs2[4], bfs3[4];
  LOADBF(bfs0, 0);
  LOADBF(bfs1, 1);
  float lpriv = 0.f;

#pragma unroll 1
  for (int gg = 0; gg < 16; ++gg) {
    ATTN_GROUP(2 * gg,     ug,  ugN, mg,  mgN);
    ATTN_GROUP(2 * gg + 1, ugN, ug,  mgN, mg);
  }

  // dump partials to LDS (each wave its own jq slice)
#pragma unroll
  for (int ct = 0; ct < 4; ct++) {
#pragma unroll
    for (int reg = 0; reg < 16; reg++) {
      const int rowl = (reg & 3) + 8 * (reg >> 2) + 4 * asel;  // verified C/D map
      red[jq][rowl][ct * 32 + am] = acc[ct][reg];
    }
  }
  lpriv += __shfl_xor(lpriv, 32);      // combine asel halves of row am
  if (asel == 0) lsum[jq][am] = lpriv;
  __syncthreads();

  // combine 4 j-quarters, normalize, ELU, store this block's 128-col slice.
  const int rr = t >> 3, cb = (t & 7) * 16;
  const float l = lsum[0][rr] + lsum[1][rr] + lsum[2][rr] + lsum[3][rr];
  const float inv = 1.0f / fmaxf(l, 1e-30f);
#pragma unroll
  for (int cc = 0; cc < 16; cc += 4) {
    float4 v;
    v.x = red[0][rr][cb + cc + 0] + red[1][rr][cb + cc + 0] + red[2][rr][cb + cc + 0] + red[3][rr][cb + cc + 0];
    v.y = red[0][rr][cb + cc + 1] + red[1][rr][cb + cc + 1] + red[2][rr][cb + cc + 1] + red[3][rr][cb + cc + 1];
    v.z = red[0][rr][cb + cc + 2] + red[1][rr][cb + cc + 2] + red[2][rr][cb + cc + 2] + red[3][rr][cb + cc + 2];
    v.w = red[0][rr][cb + cc + 3] + red[1][rr][cb + cc + 3] + red[2][rr][cb + cc + 3] + red[3][rr][cb + cc + 3];
    v.x *= inv; v.y *= inv; v.z *= inv; v.w *= inv;
    float4 o;
    o.x = v.x > 0.f ? v.x : __expf(v.x) - 1.f;
    o.y = v.y > 0.f ? v.y : __expf(v.y) - 1.f;
    o.z = v.z > 0.f ? v.z : __expf(v.z) - 1.f;
    o.w = v.w > 0.f ? v.w : __expf(v.w) - 1.f;
    *(float4*)&out[(size_t)(r0 + rr) * 256 + cg * 128 + cb + cc] = o;
  }
}

extern "C" void kernel_launch(void* const* d_in, const int* in_sizes, int n_in,
                              void* d_out, int out_size, void* d_ws, size_t ws_size,
                              hipStream_t stream) {
  const float* h  = (const float*)d_in[0];
  const int* adj  = (const int*)d_in[1];
  const float* W  = (const float*)d_in[2];
  const float* a  = (const float*)d_in[3];
  float* out = (float*)d_out;
  char* ws = (char*)d_ws;

  // ws layout:
  //  [0, 8M):    Wh fp32
  //  [8M, 16M):  mask bits (8 MB)
  //  [16M, 20M): WhT bf16 (4 MB)
  //  [20M ...):  f1 (32K), f2 (32K), uvpack (32K), f2max (128B)
  float* Wh            = (float*)ws;
  unsigned long long* mask = (unsigned long long*)(ws + (size_t)(8u << 20));
  unsigned short* WhT  = (unsigned short*)(ws + (size_t)(16u << 20));
  float* f1            = (float*)(ws + (size_t)(20u << 20));
  float* f2            = (float*)(ws + (size_t)(20u << 20) + (32u << 10));
  unsigned* uvpack     = (unsigned*)(ws + (size_t)(20u << 20) + (64u << 10));
  float* f2maxp        = (float*)(ws + (size_t)(20u << 20) + (96u << 10));

  maskgemm<<<2560, 256, 0, stream>>>(adj, mask, h, W, Wh);
  rowstats<<<2048, 256, 0, stream>>>(Wh, a, f1, f2, uvpack);
  wtrans<<<512, 256, 0, stream>>>(Wh, WhT);
  f2max_k<<<1, 256, 0, stream>>>(f2, f2maxp);
  attn_main<<<512, 256, 0, stream>>>(mask, f1, uvpack, WhT, f2maxp, out);
}

// Round 13
// 468.888 us; speedup vs baseline: 1.3256x; 1.1462x over previous
//
#include <hip/hip_runtime.h>
#include <cstdint>
#include <cstddef>

#define ALPHA 0.2f
// N=8192, Fin=512, Fout=256 hard-coded per problem instance.

typedef __attribute__((ext_vector_type(8)))  short short8;   // 8 bf16 (4 VGPRs)
typedef __attribute__((ext_vector_type(16))) float f32x16;   // 32x32 MFMA acc

static __device__ __forceinline__ unsigned short f2bf(float x) {
  union { float f; unsigned u; } c; c.f = x;
  unsigned u = c.u;
  unsigned r = (u + 0x7FFFu + ((u >> 16) & 1u)) >> 16;  // RNE
  return (unsigned short)r;
}

// ------------- Kernel A+M merged: maskpack (2048 blks) || gemm1 (512 blks) --
// Interleaved mapping: bid%5==0 -> gemm block; else mask block (r12, passed).
// Mask flush now TRANSPOSED: mask_t[it][row] so attn's per-group mask load is
// 256B contiguous (was 32 scattered lines). Same uint64 values, relocated.
__global__ __launch_bounds__(256, 2) void maskgemm(const int* __restrict__ adj,
                                                   unsigned long long* __restrict__ mask,
                                                   const float* __restrict__ h,
                                                   const float* __restrict__ W,
                                                   float* __restrict__ Wh) {
  __shared__ float As[32][68];   // [k][m], padded (gemm path)
  __shared__ float Bs[32][64];   // [k][n]   (gemm path)
  __shared__ unsigned long long mbuf[4][128];  // (mask path)
  const int t = threadIdx.x;
  const int b = blockIdx.x;
  if (b % 5 == 0) {
    // ---- gemm path (r9-verbatim tile: BM=64, BN=64, BK=32, 4x4/thread) ----
    const int bid = b / 5;
    const int nb = bid & 3, mb = bid >> 2;
    const int m0 = mb * 64, n0 = nb * 64;
    const int ty = t >> 4, tx = t & 15;
    float acc[4][4];
#pragma unroll
    for (int i = 0; i < 4; i++)
#pragma unroll
      for (int j = 0; j < 4; j++) acc[i][j] = 0.f;

    for (int k0 = 0; k0 < 512; k0 += 32) {
#pragma unroll
      for (int c = 0; c < 2; c++) {                 // stage A with transpose
        int m = c * 32 + (t >> 3);
        int kq = (t & 7) * 4;
        float4 v = *(const float4*)&h[(size_t)(m0 + m) * 512 + k0 + kq];
        As[kq + 0][m] = v.x; As[kq + 1][m] = v.y;
        As[kq + 2][m] = v.z; As[kq + 3][m] = v.w;
      }
#pragma unroll
      for (int c = 0; c < 2; c++) {                 // stage B
        int k = c * 16 + (t >> 4);
        int n = (t & 15) * 4;
        *(float4*)&Bs[k][n] = *(const float4*)&W[(size_t)(k0 + k) * 256 + n0 + n];
      }
      __syncthreads();
#pragma unroll
      for (int k = 0; k < 32; k++) {
        float4 a = *(float4*)&As[k][ty * 4];
        float4 bb = *(float4*)&Bs[k][tx * 4];
        float av[4] = {a.x, a.y, a.z, a.w};
        float bv[4] = {bb.x, bb.y, bb.z, bb.w};
#pragma unroll
        for (int i = 0; i < 4; i++)
#pragma unroll
          for (int j = 0; j < 4; j++) acc[i][j] = fmaf(av[i], bv[j], acc[i][j]);
      }
      __syncthreads();
    }
#pragma unroll
    for (int i = 0; i < 4; i++) {
      float4 v = {acc[i][0], acc[i][1], acc[i][2], acc[i][3]};
      *(float4*)&Wh[(size_t)(m0 + ty * 4 + i) * 256 + n0 + tx * 4] = v;
    }
  } else {
    // ---- maskpack path ----
    const int mask_id = b - b / 5 - 1;
    const int wave = t >> 6, lane = t & 63;
    const int row = mask_id * 4 + wave;
    const int* ap = adj + (size_t)row * 8192 + lane;
#pragma unroll 1
    for (int it0 = 0; it0 < 128; it0 += 4) {
      int a0 = ap[(it0 + 0) * 64];
      int a1 = ap[(it0 + 1) * 64];
      int a2 = ap[(it0 + 2) * 64];
      int a3 = ap[(it0 + 3) * 64];
      unsigned long long b0 = __ballot(a0 > 0);
      unsigned long long b1 = __ballot(a1 > 0);
      unsigned long long b2 = __ballot(a2 > 0);
      unsigned long long b3 = __ballot(a3 > 0);
      if (lane == 0) {
        mbuf[wave][it0 + 0] = b0; mbuf[wave][it0 + 1] = b1;
        mbuf[wave][it0 + 2] = b2; mbuf[wave][it0 + 3] = b3;
      }
    }
    __syncthreads();
    // transposed flush: mask_t[it][row]; thread t: it = t&127, half = t>>7
    // writes rows row0+2*half .. +2*half+1 (16B aligned: row0%4==0).
    const int it = t & 127, half = t >> 7;
    const int row0 = mask_id * 4;
    unsigned long long tmp[2] = {mbuf[half * 2][it], mbuf[half * 2 + 1][it]};
    *(uint4*)&mask[(size_t)it * 8192 + row0 + half * 2] = *(const uint4*)tmp;
  }
}

// ------------- Kernel B: per-row f1,f2 and u/v pack (verbatim) --------------
__global__ __launch_bounds__(256) void rowstats(const float* __restrict__ Wh,
                                                const float* __restrict__ a,
                                                float* __restrict__ f1,
                                                float* __restrict__ f2,
                                                unsigned* __restrict__ uvpack) {
  const int t = threadIdx.x;
  const int w = t >> 6, lane = t & 63;
  const int i = blockIdx.x * 4 + w;
  float4 wv = *(const float4*)&Wh[(size_t)i * 256 + lane * 4];
  float4 a1 = *(const float4*)&a[lane * 4];
  float4 a2 = *(const float4*)&a[256 + lane * 4];
  float s1 = wv.x * a1.x + wv.y * a1.y + wv.z * a1.z + wv.w * a1.w;
  float s2 = wv.x * a2.x + wv.y * a2.y + wv.z * a2.z + wv.w * a2.w;
#pragma unroll
  for (int off = 32; off; off >>= 1) { s1 += __shfl_xor(s1, off); s2 += __shfl_xor(s2, off); }
  if (lane == 0) {
    f1[i] = s1; f2[i] = s2;
    float u = __expf(s2), v = __expf(ALPHA * s2);
    uvpack[i] = (unsigned)f2bf(u) | ((unsigned)f2bf(v) << 16);
  }
}

// ------------- Kernel B2: pack Wh into MFMA B-fragment layout ---------------
// BP[c32][s][lane][e] (bf16) = f2bf(Wh[s*16 + (lane>>5)*8 + e][c32*32 + (lane&31)])
// = exactly the short8 each attn lane needs for fragment (c32, s): attn's
// B-load becomes ONE coalesced 1KB wave-load (16 sequential lines) instead of
// 32 scattered lines at 16KB stride. Register contents bit-identical to the
// old WhT loads. grid 128 = 8 c32 x 16 sblk; wave packs 8 s values.
__global__ __launch_bounds__(256) void bpack(const float* __restrict__ Wh,
                                             unsigned short* __restrict__ BP) {
  const int t = threadIdx.x, wave = t >> 6, lane = t & 63;
  const int c32 = blockIdx.x >> 4, sblk = blockIdx.x & 15;
  const int col = c32 * 32 + (lane & 31), hi = lane >> 5;
#pragma unroll
  for (int p = 0; p < 8; p++) {
    const int s = sblk * 32 + wave * 8 + p;
    unsigned short v[8];
#pragma unroll
    for (int e = 0; e < 8; e++)
      v[e] = f2bf(Wh[(size_t)(s * 16 + hi * 8 + e) * 256 + col]);
    *(uint4*)&BP[((size_t)c32 * 512 + s) * 512 + lane * 8] = *(const uint4*)v;
  }
}

// ---------------- Kernel Bmax: F2max = max_j f2[j] --------------------------
__global__ __launch_bounds__(256) void f2max_k(const float* __restrict__ f2,
                                               float* __restrict__ f2maxp) {
  __shared__ float red[256];
  const int t = threadIdx.x;
  float m = -1e30f;
  for (int c = 0; c < 32; c++) m = fmaxf(m, f2[c * 256 + t]);
  red[t] = m;
  __syncthreads();
  for (int s = 128; s; s >>= 1) {
    if (t < s) red[t] = fmaxf(red[t], red[t + s]);
    __syncthreads();
  }
  if (t == 0) f2maxp[0] = red[0];
}

// ---------------- Kernel C: fused masked-softmax @ Wh -----------------------
// r12 structure (passing: cg-block split, quad-buffer, (256,1)) with the two
// layout swaps: (a) B-fragments from BP -> coalesced 1KB loads; (b) mask from
// mask_t[it][row] -> 256B contiguous per group. Same register contents, same
// MFMA/accumulate order -> bit-identical output.
// KEEP __launch_bounds__(256,1): (256,2) silently zeroes output (r10/r11).
#define LOADBF(BUF, SIDX)                                                        \
  {                                                                              \
    const int s_ = (SIDX) < 128 ? (SIDX) : 127;                                  \
    BUF[0] = *(const short8*)(bp0 + (size_t)(0 * 512 + s_) * 512);               \
    BUF[1] = *(const short8*)(bp0 + (size_t)(1 * 512 + s_) * 512);               \
    BUF[2] = *(const short8*)(bp0 + (size_t)(2 * 512 + s_) * 512);               \
    BUF[3] = *(const short8*)(bp0 + (size_t)(3 * 512 + s_) * 512);               \
  }

#define ATTN_SUB(KSUB, MWORD, UCA, UCB, BFC)                                     \
  {                                                                              \
    const unsigned mbyte_ = ((MWORD) >> (((KSUB) & 1) * 16 + aselsh)) & 0xFFu;   \
    const unsigned uu_[8] = {UCA.x, UCA.y, UCA.z, UCA.w, UCB.x, UCB.y, UCB.z, UCB.w}; \
    float w_[8];                                                                 \
    _Pragma("unroll")                                                            \
    for (int jj = 0; jj < 8; jj++) {                                             \
      union { unsigned u; float f; } cu_, cv_;                                   \
      cu_.u = uu_[jj] << 16;                                                     \
      cv_.u = uu_[jj] & 0xFFFF0000u;                                             \
      float wv_ = (cu_.f > Ui) ? Ai * cu_.f : Bi * cv_.f;                        \
      int ext_ = ((int)(mbyte_ << (31 - jj))) >> 31;   /* bit -> 0 / all-ones */ \
      union { float f; int i; } wu_; wu_.f = wv_; wu_.i &= ext_;                 \
      w_[jj] = wu_.f;                                                            \
    }                                                                            \
    lpriv += ((w_[0] + w_[1]) + (w_[2] + w_[3])) + ((w_[4] + w_[5]) + (w_[6] + w_[7])); \
    union { uint4 q; short8 s; } af_;                                            \
    asm("v_cvt_pk_bf16_f32 %0, %1, %2" : "=v"(af_.q.x) : "v"(w_[0]), "v"(w_[1]));\
    asm("v_cvt_pk_bf16_f32 %0, %1, %2" : "=v"(af_.q.y) : "v"(w_[2]), "v"(w_[3]));\
    asm("v_cvt_pk_bf16_f32 %0, %1, %2" : "=v"(af_.q.z) : "v"(w_[4]), "v"(w_[5]));\
    asm("v_cvt_pk_bf16_f32 %0, %1, %2" : "=v"(af_.q.w) : "v"(w_[6]), "v"(w_[7]));\
    acc[0] = __builtin_amdgcn_mfma_f32_32x32x16_bf16(af_.s, BFC[0], acc[0], 0, 0, 0); \
    acc[1] = __builtin_amdgcn_mfma_f32_32x32x16_bf16(af_.s, BFC[1], acc[1], 0, 0, 0); \
    acc[2] = __builtin_amdgcn_mfma_f32_32x32x16_bf16(af_.s, BFC[2], acc[2], 0, 0, 0); \
    acc[3] = __builtin_amdgcn_mfma_f32_32x32x16_bf16(af_.s, BFC[3], acc[3], 0, 0, 0); \
  }

#define ATTN_GROUP(G, UC, UN, MC, MN)                                            \
  {                                                                              \
    const int gn_ = (G) < 31 ? (G) + 1 : 31;                                     \
    MN = mp[(size_t)gn_ * 8192];                                                 \
    UN[0] = *(const uint4*)(uvp + gn_ * 64 + 0);                                 \
    UN[1] = *(const uint4*)(uvp + gn_ * 64 + 4);                                 \
    LOADBF(bfs2, 4 * (G) + 2);           /* prefetch 2-3 steps ahead        */  \
    LOADBF(bfs3, 4 * (G) + 3);                                                   \
    ATTN_SUB(0, MC.x, UC[0], UC[1], bfs0);                                       \
    UN[2] = *(const uint4*)(uvp + gn_ * 64 + 16);                                \
    UN[3] = *(const uint4*)(uvp + gn_ * 64 + 20);                                \
    ATTN_SUB(1, MC.x, UC[2], UC[3], bfs1);                                       \
    UN[4] = *(const uint4*)(uvp + gn_ * 64 + 32);                                \
    UN[5] = *(const uint4*)(uvp + gn_ * 64 + 36);                                \
    LOADBF(bfs0, 4 * (G) + 4);           /* next group's first pair         */  \
    LOADBF(bfs1, 4 * (G) + 5);                                                   \
    ATTN_SUB(2, MC.y, UC[4], UC[5], bfs2);                                       \
    UN[6] = *(const uint4*)(uvp + gn_ * 64 + 48);                                \
    UN[7] = *(const uint4*)(uvp + gn_ * 64 + 52);                                \
    ATTN_SUB(3, MC.y, UC[6], UC[7], bfs3);                                       \
  }

__global__ __launch_bounds__(256, 1) void attn_main(const unsigned long long* __restrict__ maskw,
                                                    const float* __restrict__ f1,
                                                    const unsigned* __restrict__ uvpack,
                                                    const unsigned short* __restrict__ BP,
                                                    const float* __restrict__ f2maxp,
                                                    float* __restrict__ out) {
  __shared__ float red[4][32][132];   // 4 jq x 32 rows x 128 cols (+4 pad); 67.6 KB
  __shared__ float lsum[4][32];
  const int t = threadIdx.x;
  const int wave = t >> 6, lane = t & 63;
  const int jq = wave;                  // each wave owns a j-quarter
  const int am = lane & 31, asel = lane >> 5;
  const int aselsh = asel * 8;
  const int bid = blockIdx.x;
  const int cg = bid & 1;               // col-group from block
  const int r0 = (bid >> 1) * 32;
  const int row = r0 + am;

  const float F2max = f2maxp[0];
  const float f1v = f1[row];
  const float x = f1v + F2max;
  const float M = x > 0.f ? x : ALPHA * x;   // analytic per-row max bound
  const float Ai = __expf(f1v - M);
  const float Bi = __expf(ALPHA * f1v - M);
  const float Ui = __expf(-f1v);             // u_j > Ui  <=>  f1_i + f2_j > 0

  f32x16 acc[4] = {};
  // streams: mask_t[it][row] (contiguous across lanes); uv broadcast;
  // BP fragment-packed (contiguous 1KB per fragment).
  const uint2* mp = (const uint2*)maskw + (size_t)(jq * 32) * 8192 + row;
  const unsigned* uvp = uvpack + jq * 2048 + aselsh;
  const unsigned short* bp0 = BP + ((size_t)(cg * 4) * 512 + jq * 128) * 512 + lane * 8;

  // prologue: group-0 mask+uv; bf steps 0 and 1
  uint2 mg = mp[0], mgN;
  uint4 ug[8], ugN[8];
#pragma unroll
  for (int k = 0; k < 4; k++) {
    ug[2 * k]     = *(const uint4*)(uvp + k * 16);
    ug[2 * k + 1] = *(const uint4*)(uvp + k * 16 + 4);
  }
  short8 bfs0[4], bfs1[4], bfs2[4], bfs3[4];
  LOADBF(bfs0, 0);
  LOADBF(bfs1, 1);
  float lpriv = 0.f;

#pragma unroll 1
  for (int gg = 0; gg < 16; ++gg) {
    ATTN_GROUP(2 * gg,     ug,  ugN, mg,  mgN);
    ATTN_GROUP(2 * gg + 1, ugN, ug,  mgN, mg);
  }

  // dump partials to LDS (each wave its own jq slice)
#pragma unroll
  for (int ct = 0; ct < 4; ct++) {
#pragma unroll
    for (int reg = 0; reg < 16; reg++) {
      const int rowl = (reg & 3) + 8 * (reg >> 2) + 4 * asel;  // verified C/D map
      red[jq][rowl][ct * 32 + am] = acc[ct][reg];
    }
  }
  lpriv += __shfl_xor(lpriv, 32);      // combine asel halves of row am
  if (asel == 0) lsum[jq][am] = lpriv;
  __syncthreads();

  // combine 4 j-quarters, normalize, ELU, store this block's 128-col slice.
  const int rr = t >> 3, cb = (t & 7) * 16;
  const float l = lsum[0][rr] + lsum[1][rr] + lsum[2][rr] + lsum[3][rr];
  const float inv = 1.0f / fmaxf(l, 1e-30f);
#pragma unroll
  for (int cc = 0; cc < 16; cc += 4) {
    float4 v;
    v.x = red[0][rr][cb + cc + 0] + red[1][rr][cb + cc + 0] + red[2][rr][cb + cc + 0] + red[3][rr][cb + cc + 0];
    v.y = red[0][rr][cb + cc + 1] + red[1][rr][cb + cc + 1] + red[2][rr][cb + cc + 1] + red[3][rr][cb + cc + 1];
    v.z = red[0][rr][cb + cc + 2] + red[1][rr][cb + cc + 2] + red[2][rr][cb + cc + 2] + red[3][rr][cb + cc + 2];
    v.w = red[0][rr][cb + cc + 3] + red[1][rr][cb + cc + 3] + red[2][rr][cb + cc + 3] + red[3][rr][cb + cc + 3];
    v.x *= inv; v.y *= inv; v.z *= inv; v.w *= inv;
    float4 o;
    o.x = v.x > 0.f ? v.x : __expf(v.x) - 1.f;
    o.y = v.y > 0.f ? v.y : __expf(v.y) - 1.f;
    o.z = v.z > 0.f ? v.z : __expf(v.z) - 1.f;
    o.w = v.w > 0.f ? v.w : __expf(v.w) - 1.f;
    *(float4*)&out[(size_t)(r0 + rr) * 256 + cg * 128 + cb + cc] = o;
  }
}

extern "C" void kernel_launch(void* const* d_in, const int* in_sizes, int n_in,
                              void* d_out, int out_size, void* d_ws, size_t ws_size,
                              hipStream_t stream) {
  const float* h  = (const float*)d_in[0];
  const int* adj  = (const int*)d_in[1];
  const float* W  = (const float*)d_in[2];
  const float* a  = (const float*)d_in[3];
  float* out = (float*)d_out;
  char* ws = (char*)d_ws;

  // ws layout:
  //  [0, 8M):    Wh fp32
  //  [8M, 16M):  mask_t bits (8 MB, [it][row])
  //  [16M, 20M): BP bf16 fragment-packed (4 MB)
  //  [20M ...):  f1 (32K), f2 (32K), uvpack (32K), f2max (128B)
  float* Wh            = (float*)ws;
  unsigned long long* mask = (unsigned long long*)(ws + (size_t)(8u << 20));
  unsigned short* BP   = (unsigned short*)(ws + (size_t)(16u << 20));
  float* f1            = (float*)(ws + (size_t)(20u << 20));
  float* f2            = (float*)(ws + (size_t)(20u << 20) + (32u << 10));
  unsigned* uvpack     = (unsigned*)(ws + (size_t)(20u << 20) + (64u << 10));
  float* f2maxp        = (float*)(ws + (size_t)(20u << 20) + (96u << 10));

  maskgemm<<<2560, 256, 0, stream>>>(adj, mask, h, W, Wh);
  rowstats<<<2048, 256, 0, stream>>>(Wh, a, f1, f2, uvpack);
  bpack<<<128, 256, 0, stream>>>(Wh, BP);
  f2max_k<<<1, 256, 0, stream>>>(f2, f2maxp);
  attn_main<<<512, 256, 0, stream>>>(mask, f1, uvpack, BP, f2maxp, out);
}